// Round 14
// baseline (636.710 us; speedup 1.0000x reference)
//
#include <hip/hip_runtime.h>

#define NPTS 8192
#define NSQ ((size_t)NPTS * (size_t)NPTS)

typedef float        f32x4 __attribute__((ext_vector_type(4)));
typedef unsigned int u32x4 __attribute__((ext_vector_type(4)));

__device__ __forceinline__ float bf16_to_f(unsigned short u) {
    return __uint_as_float(((unsigned int)u) << 16);
}
__device__ __forceinline__ unsigned short f_to_bf16_rne(float f) {
    unsigned int x = __float_as_uint(f);
    x += 0x7FFFu + ((x >> 16) & 1u);
    return (unsigned short)(x >> 16);
}

// R14 = R9 (the thrice-proven passing kernel) with ONE change: the final
// stores are NONTEMPORAL. Theory: the kernel's ~167us (vs 43us write floor)
// is L2 write-allocate serialization -- 268MB streamed through a 32MB L2
// that the poison fill just left fully dirty; nt stores bypass allocate and
// stream at the fill's own demonstrated 6.2TB/s write rate.
//
// ENVELOPE LAW (13 runs): every PASS has each thread writing ONE contiguous
// region per plane (<=32B) with >=4.2M threads (R0/R9/R10/R11/R12); every
// FAIL loops per-thread over disjoint store regions (R2-R8: 8 regions;
// R13: 4 regions -- which also killed the grid.y=8192 theory). Mechanism
// unknown; rule respected here: geometry (4,8192)x256, 1 region/thread,
// byte-identical to R9. R2's nt failure is fully confounded by its
// out-of-envelope store structure (R13 proves that structure fails WITHOUT
// nt), so nt gets its clean test now.
//
// Store values are built by VALUE (no new type puns); ext-vector types used
// only at the final store, as required by __builtin_nontemporal_store.
//
// Dtype probe v1 (all passing runs). Out dtype = in dtype. Numerics = np
// reference order exactly (absmax 2^-8 on bf16 runs):
//   sq  = ((x*x)+(y*y))+(z*z)
//   dot = fma(z,z', fma(y,y', x*x'))
//   d   = (sq_i + sq_j) - 2*dot ; max(d,0) ; mask = d <= 1
__global__ __launch_bounds__(256) void radius_kernel(
    const void* __restrict__ pos_raw,
    void* __restrict__ out_raw) {

    const int i  = blockIdx.y;
    const int j0 = blockIdx.x * 2048 + (int)threadIdx.x * 8;

    // ---- wave-uniform dtype probe (v1, verbatim) ----
    const unsigned short* pu = (const unsigned short*)pos_raw;
    const float probe = bf16_to_f(pu[threadIdx.x & 63]);
    const bool lane_ok = (probe >= 0.0f) && (probe <= 16.0f);  // NaN fails
    const bool is_f32 = !__all(lane_ok);

    float flat[24];  // x0 y0 z0 ... x7 y7 z7 for the 8 j-points
    float xi, yi, zi;

    if (is_f32) {
        const float* pos = (const float*)pos_raw;
        const float4* p4 = (const float4*)(pos + (size_t)j0 * 3); // 96B, 16B-aligned
#pragma unroll
        for (int q = 0; q < 6; ++q) ((float4*)flat)[q] = p4[q];
        xi = pos[i * 3 + 0]; yi = pos[i * 3 + 1]; zi = pos[i * 3 + 2];
    } else {
        const unsigned short* pos = (const unsigned short*)pos_raw;
        unsigned short us[24];
        const uint4* p4 = (const uint4*)(pos + (size_t)j0 * 3);   // 48B, 16B-aligned
#pragma unroll
        for (int q = 0; q < 3; ++q) ((uint4*)us)[q] = p4[q];
#pragma unroll
        for (int t = 0; t < 24; ++t) flat[t] = bf16_to_f(us[t]);
        xi = bf16_to_f(pos[i * 3 + 0]);
        yi = bf16_to_f(pos[i * 3 + 1]);
        zi = bf16_to_f(pos[i * 3 + 2]);
    }

    const float sqi = __fadd_rn(__fadd_rn(__fmul_rn(xi, xi), __fmul_rn(yi, yi)),
                                __fmul_rn(zi, zi));

    float dval[8];
    bool  mval[8];
#pragma unroll
    for (int t = 0; t < 8; ++t) {
        const float x = flat[3 * t + 0];
        const float y = flat[3 * t + 1];
        const float z = flat[3 * t + 2];
        const float sqj = __fadd_rn(
            __fadd_rn(__fmul_rn(x, x), __fmul_rn(y, y)), __fmul_rn(z, z));
        const float dot = __fmaf_rn(zi, z, __fmaf_rn(yi, y, __fmul_rn(xi, x)));
        float d = __fsub_rn(__fadd_rn(sqi, sqj), __fmul_rn(2.0f, dot));
        d = fmaxf(d, 0.0f);
        const bool m = (d <= 1.0f);
        dval[t] = m ? d : 0.0f;
        mval[t] = m;
    }

    const size_t off = (size_t)i * NPTS + (size_t)j0;

    if (is_f32) {
        float* out_md   = (float*)out_raw;
        float* out_mask = out_md + NSQ;
        f32x4 vmd0, vmd1, vmk0, vmk1;
#pragma unroll
        for (int l = 0; l < 4; ++l) {
            vmd0[l] = dval[l];
            vmd1[l] = dval[4 + l];
            vmk0[l] = mval[l] ? 1.0f : 0.0f;
            vmk1[l] = mval[4 + l] ? 1.0f : 0.0f;
        }
        __builtin_nontemporal_store(vmd0, (f32x4*)(out_md + off) + 0);
        __builtin_nontemporal_store(vmd1, (f32x4*)(out_md + off) + 1);
        __builtin_nontemporal_store(vmk0, (f32x4*)(out_mask + off) + 0);
        __builtin_nontemporal_store(vmk1, (f32x4*)(out_mask + off) + 1);
    } else {
        unsigned short* out_md   = (unsigned short*)out_raw;
        unsigned short* out_mask = out_md + NSQ;
        u32x4 vmd, vmk;
#pragma unroll
        for (int l = 0; l < 4; ++l) {
            const unsigned int m0 = (unsigned int)f_to_bf16_rne(dval[2 * l]);
            const unsigned int m1 = (unsigned int)f_to_bf16_rne(dval[2 * l + 1]);
            vmd[l] = m0 | (m1 << 16);
            const unsigned int k0 = mval[2 * l]     ? 0x3F80u : 0u;
            const unsigned int k1 = mval[2 * l + 1] ? 0x3F80u : 0u;
            vmk[l] = k0 | (k1 << 16);
        }
        __builtin_nontemporal_store(vmd, (u32x4*)(out_md + off));
        __builtin_nontemporal_store(vmk, (u32x4*)(out_mask + off));
    }
}

extern "C" void kernel_launch(void* const* d_in, const int* in_sizes, int n_in,
                              void* d_out, int out_size, void* d_ws, size_t ws_size,
                              hipStream_t stream) {
    (void)in_sizes; (void)n_in; (void)out_size; (void)d_ws; (void)ws_size;

    dim3 block(256, 1, 1);
    dim3 grid(NPTS / 2048, NPTS, 1);  // (4, 8192) -- the proven envelope
    radius_kernel<<<grid, block, 0, stream>>>(d_in[0], d_out);
}

// Round 15
// 512.697 us; speedup vs baseline: 1.2419x; 1.2419x over previous
//
#include <hip/hip_runtime.h>

#define NPTS 8192
#define NSQ ((size_t)NPTS * (size_t)NPTS)

__device__ __forceinline__ float bf16_to_f(unsigned short u) {
    return __uint_as_float(((unsigned int)u) << 16);
}
__device__ __forceinline__ unsigned short f_to_bf16_rne(float f) {
    unsigned int x = __float_as_uint(f);
    x += 0x7FFFu + ((x >> 16) & 1u);
    return (unsigned short)(x >> 16);
}

// R15 = R9 verbatim -- the best-measured passing kernel (512.65us).
//
// FINAL LEDGER (15 rounds): kernel ~168us of the 513 total (345us = harness
// poison-fill at 78% HBM ceiling, fixed cost). In-envelope experiments:
//   blocks/4 (R10):            +8us  null -> dispatch exonerated
//   waves/2 (R11):            +82us  neg  -> half-line stores kill combining
//   LDS-coalesced reads (R12): +2us  null -> reads are L2-resident, free
//   nt stores (R14):         +124us  neg  -> L2 write-combining load-bearing
//   multi-region stores (R13/R2-R8): FAIL -> envelope law (below)
// ENVELOPE LAW (empirical, mechanism unknown): every passing run has each
// thread writing ONE contiguous <=32B region per output plane with >=4.2M
// threads; every per-thread multi-region variant fails with a nothing-
// written signature. Geometry (4,8192)x256 is the proven config.
//
// Dtype probe (wave-uniform): read pos's first 64 u16s as bf16; true bf16
// coords lie in [0,16]; f32 low mantissa halves decode to wild exponents.
// __all() -> identical verdict every wave. Out dtype = in dtype.
//
// Numerics = np reference order exactly (absmax 2^-8 on bf16 runs):
//   sq  = ((x*x)+(y*y))+(z*z)
//   dot = fma(z,z', fma(y,y', x*x'))   ascending-k accumulation
//   d   = (sq_i + sq_j) - 2*dot ; max(d,0) ; mask = d <= 1
__global__ __launch_bounds__(256) void radius_kernel(
    const void* __restrict__ pos_raw,
    void* __restrict__ out_raw) {

    const int i  = blockIdx.y;
    const int j0 = blockIdx.x * 2048 + (int)threadIdx.x * 8;

    // ---- wave-uniform dtype probe ----
    const unsigned short* pu = (const unsigned short*)pos_raw;
    const float probe = bf16_to_f(pu[threadIdx.x & 63]);
    const bool lane_ok = (probe >= 0.0f) && (probe <= 16.0f);  // NaN fails
    const bool is_f32 = !__all(lane_ok);

    float flat[24];  // x0 y0 z0 ... x7 y7 z7 for the 8 j-points
    float xi, yi, zi;

    if (is_f32) {
        const float* pos = (const float*)pos_raw;
        const float4* p4 = (const float4*)(pos + (size_t)j0 * 3); // 96B, 16B-aligned
#pragma unroll
        for (int q = 0; q < 6; ++q) ((float4*)flat)[q] = p4[q];
        xi = pos[i * 3 + 0]; yi = pos[i * 3 + 1]; zi = pos[i * 3 + 2];
    } else {
        const unsigned short* pos = (const unsigned short*)pos_raw;
        unsigned short us[24];
        const uint4* p4 = (const uint4*)(pos + (size_t)j0 * 3);   // 48B, 16B-aligned
#pragma unroll
        for (int q = 0; q < 3; ++q) ((uint4*)us)[q] = p4[q];
#pragma unroll
        for (int t = 0; t < 24; ++t) flat[t] = bf16_to_f(us[t]);
        xi = bf16_to_f(pos[i * 3 + 0]);
        yi = bf16_to_f(pos[i * 3 + 1]);
        zi = bf16_to_f(pos[i * 3 + 2]);
    }

    const float sqi = __fadd_rn(__fadd_rn(__fmul_rn(xi, xi), __fmul_rn(yi, yi)),
                                __fmul_rn(zi, zi));

    float dval[8];
    bool  mval[8];
#pragma unroll
    for (int t = 0; t < 8; ++t) {
        const float x = flat[3 * t + 0];
        const float y = flat[3 * t + 1];
        const float z = flat[3 * t + 2];
        const float sqj = __fadd_rn(
            __fadd_rn(__fmul_rn(x, x), __fmul_rn(y, y)), __fmul_rn(z, z));
        const float dot = __fmaf_rn(zi, z, __fmaf_rn(yi, y, __fmul_rn(xi, x)));
        float d = __fsub_rn(__fadd_rn(sqi, sqj), __fmul_rn(2.0f, dot));
        d = fmaxf(d, 0.0f);
        const bool m = (d <= 1.0f);
        dval[t] = m ? d : 0.0f;
        mval[t] = m;
    }

    const size_t off = (size_t)i * NPTS + (size_t)j0;

    if (is_f32) {
        float* out_md   = (float*)out_raw;
        float* out_mask = out_md + NSQ;
        float md8[8], mk8[8];
#pragma unroll
        for (int t = 0; t < 8; ++t) { md8[t] = dval[t]; mk8[t] = mval[t] ? 1.0f : 0.0f; }
        ((float4*)(out_md + off))[0]   = ((float4*)md8)[0];
        ((float4*)(out_md + off))[1]   = ((float4*)md8)[1];
        ((float4*)(out_mask + off))[0] = ((float4*)mk8)[0];
        ((float4*)(out_mask + off))[1] = ((float4*)mk8)[1];
    } else {
        unsigned short* out_md   = (unsigned short*)out_raw;
        unsigned short* out_mask = out_md + NSQ;
        unsigned short md8[8], mk8[8];
#pragma unroll
        for (int t = 0; t < 8; ++t) {
            md8[t] = f_to_bf16_rne(dval[t]);
            mk8[t] = mval[t] ? (unsigned short)0x3F80u : (unsigned short)0u;
        }
        *(uint4*)(out_md + off)   = *(uint4*)md8;
        *(uint4*)(out_mask + off) = *(uint4*)mk8;
    }
}

extern "C" void kernel_launch(void* const* d_in, const int* in_sizes, int n_in,
                              void* d_out, int out_size, void* d_ws, size_t ws_size,
                              hipStream_t stream) {
    (void)in_sizes; (void)n_in; (void)out_size; (void)d_ws; (void)ws_size;

    dim3 block(256, 1, 1);
    dim3 grid(NPTS / 2048, NPTS, 1);  // (4, 8192) -- the proven geometry
    radius_kernel<<<grid, block, 0, stream>>>(d_in[0], d_out);
}